// Round 1
// baseline (16406.888 us; speedup 1.0000x reference)
//
#include <hip/hip_runtime.h>
#include <cmath>

namespace {

constexpr int NH = 1024;
constexpr int NG = 4096;   // 4*H
constexpr int NV = 32000;
constexpr int NT = 64;

// ---------------- zero slot0 of the 8 state-history buffers ----------------
__global__ __launch_bounds__(256) void zero_slot0(float* hb) {
  int idx = blockIdx.x * 256 + threadIdx.x;         // 0..65535 (8 hists * 8192 f4)
  int h = idx >> 13, e4 = idx & 8191;
  float4 z{0.f, 0.f, 0.f, 0.f};
  *(float4*)&hb[(size_t)h * (65ull * 32 * NH) + (size_t)e4 * 4] = z;
}

// ---------------- embedding gather for source and prev_outputs -------------
__global__ __launch_bounds__(256) void embed_kernel(
    const int* __restrict__ src, const int* __restrict__ prev,
    const float* __restrict__ emb, float* __restrict__ se, float* __restrict__ te) {
  int idx = blockIdx.x * 256 + threadIdx.x;         // 0..524287
  int half = idx >> 18;                             // 0: src, 1: tgt
  int r = (idx >> 7) & 2047;                        // row = s*32+b
  int c4 = idx & 127;
  int s = r >> 5, b = r & 31;
  const int* tok = half ? prev : src;
  float* dst = half ? te : se;
  int t = tok[b * 64 + s];
  *(float4*)&dst[(size_t)r * 512 + c4 * 4] =
      *(const float4*)&emb[(size_t)t * 512 + c4 * 4];
}

// ---------------- copy encoder final states -> decoder slot0 ---------------
__global__ __launch_bounds__(256) void init_dec_state(
    const float* __restrict__ h0f, const float* __restrict__ c0f,
    const float* __restrict__ h1f, const float* __restrict__ c1f,
    float* __restrict__ dh0, float* __restrict__ dc0,
    float* __restrict__ dh1, float* __restrict__ dc1) {
  int idx = blockIdx.x * 256 + threadIdx.x;         // 0..32767 (4 * 8192 f4)
  int w = idx >> 13, e4 = (idx & 8191) * 4;
  const float* s = (w == 0) ? h0f : (w == 1) ? c0f : (w == 2) ? h1f : c1f;
  float* d = (w == 0) ? dh0 : (w == 1) ? dc0 : (w == 2) ? dh1 : dc1;
  *(float4*)&d[e4] = *(const float4*)&s[e4];
}

// ---------------- generic fp32 GEMM: C[M][N] = A[M][K] * W[N][ldw]^T + bias -
// tile 64x64, 256 threads, 4x4 per thread. REMAP=1: row r=(t*32+b) scattered
// to out[b][t][n] (logits layout).
template<int REMAP>
__global__ __launch_bounds__(256) void gemm_tn(
    const float* __restrict__ A, int lda,
    const float* __restrict__ W, int ldw,
    const float* __restrict__ bias,
    float* __restrict__ C, int ldc, int K) {
  __shared__ float As[16 * 68];
  __shared__ float Bs[16 * 68];
  int tid = threadIdx.x;
  int n0 = blockIdx.x * 64, m0 = blockIdx.y * 64;
  int lm = tid >> 2, lk = (tid & 3) * 4;
  int tx = tid & 15, ty = tid >> 4;
  float acc[4][4] = {};
  const float* Ap = A + (size_t)(m0 + lm) * lda + lk;
  const float* Wp = W + (size_t)(n0 + lm) * ldw + lk;
  for (int k0 = 0; k0 < K; k0 += 16) {
    float4 av = *(const float4*)(Ap + k0);
    float4 bv = *(const float4*)(Wp + k0);
    __syncthreads();
    As[(lk + 0) * 68 + lm] = av.x; As[(lk + 1) * 68 + lm] = av.y;
    As[(lk + 2) * 68 + lm] = av.z; As[(lk + 3) * 68 + lm] = av.w;
    Bs[(lk + 0) * 68 + lm] = bv.x; Bs[(lk + 1) * 68 + lm] = bv.y;
    Bs[(lk + 2) * 68 + lm] = bv.z; Bs[(lk + 3) * 68 + lm] = bv.w;
    __syncthreads();
#pragma unroll
    for (int k = 0; k < 16; k++) {
      float4 a4 = *(const float4*)&As[k * 68 + ty * 4];
      float4 b4 = *(const float4*)&Bs[k * 68 + tx * 4];
      const float* ap = (const float*)&a4;
      const float* bp = (const float*)&b4;
#pragma unroll
      for (int i = 0; i < 4; i++)
#pragma unroll
        for (int j = 0; j < 4; j++)
          acc[i][j] += ap[i] * bp[j];
    }
  }
#pragma unroll
  for (int i = 0; i < 4; i++) {
    int m = m0 + ty * 4 + i;
#pragma unroll
    for (int j = 0; j < 4; j++) {
      int n = n0 + tx * 4 + j;
      float v = acc[i][j] + bias[n];
      if (REMAP) {
        C[(size_t)(m & 31) * ((size_t)NT * NV) + (size_t)(m >> 5) * NV + n] = v;
      } else {
        C[(size_t)m * ldc + n] = v;
      }
    }
  }
}

// ---------------- fused LSTM step -----------------------------------------
// gates[b][g*1024+u] = (gx?)+(bias?) + A1[b]·W1[g*1024+u] (+ A2[b]·W2[...])
// then i,f,g,o activations + state update. Block: 32 b x 8 u; grid 128.
template<int DUAL>
__global__ __launch_bounds__(256) void lstm_step(
    const float* __restrict__ gx, const float* __restrict__ bias,
    const float* __restrict__ A1, const float* __restrict__ W1, int ld1,
    const float* __restrict__ A2, const float* __restrict__ W2, int ld2,
    const float* __restrict__ cprev,
    float* __restrict__ hout, float* __restrict__ cout) {
  __shared__ float As1[32 * 68];
  __shared__ float W1s[32 * 64];
  __shared__ float As2[DUAL ? 32 * 68 : 4];
  __shared__ float W2s[DUAL ? 32 * 64 : 4];
  int tid = threadIdx.x;
  int u0 = blockIdx.x * 8;
  int b = tid & 31, ui = tid >> 5;
  float acc[4] = {0.f, 0.f, 0.f, 0.f};
  for (int k0 = 0; k0 < NH; k0 += 64) {
    __syncthreads();
#pragma unroll
    for (int i = 0; i < 2; i++) {
      int idx = tid + i * 256;                       // 0..511
      int row = idx >> 4, k4 = idx & 15;             // 32 rows x 16 f4
      float4 av = *(const float4*)&A1[(size_t)row * NH + k0 + k4 * 4];
      *(float4*)&As1[row * 68 + k4 * 4] = av;
      int grow = (row >> 3) * NH + u0 + (row & 7);   // gate*1024 + u
      float4 wv = *(const float4*)&W1[(size_t)grow * ld1 + k0 + k4 * 4];
      *(float4*)&W1s[row * 64 + k4 * 4] = wv;
      if (DUAL) {
        float4 av2 = *(const float4*)&A2[(size_t)row * NH + k0 + k4 * 4];
        *(float4*)&As2[row * 68 + k4 * 4] = av2;
        float4 wv2 = *(const float4*)&W2[(size_t)grow * ld2 + k0 + k4 * 4];
        *(float4*)&W2s[row * 64 + k4 * 4] = wv2;
      }
    }
    __syncthreads();
#pragma unroll
    for (int k4 = 0; k4 < 16; k4++) {
      float4 a = *(const float4*)&As1[b * 68 + k4 * 4];
      const float* ap = (const float*)&a;
#pragma unroll
      for (int g = 0; g < 4; g++) {
        float4 w = *(const float4*)&W1s[(g * 8 + ui) * 64 + k4 * 4];
        const float* wp = (const float*)&w;
        acc[g] += ap[0] * wp[0] + ap[1] * wp[1] + ap[2] * wp[2] + ap[3] * wp[3];
      }
      if (DUAL) {
        float4 a2 = *(const float4*)&As2[b * 68 + k4 * 4];
        const float* ap2 = (const float*)&a2;
#pragma unroll
        for (int g = 0; g < 4; g++) {
          float4 w2 = *(const float4*)&W2s[(g * 8 + ui) * 64 + k4 * 4];
          const float* wp2 = (const float*)&w2;
          acc[g] += ap2[0] * wp2[0] + ap2[1] * wp2[1] + ap2[2] * wp2[2] + ap2[3] * wp2[3];
        }
      }
    }
  }
  int u = u0 + ui;
  float gi = acc[0], gf = acc[1], gg = acc[2], go = acc[3];
  if (gx) {
    int base = b * NG + u;
    gi += gx[base]; gf += gx[base + NH]; gg += gx[base + 2 * NH]; go += gx[base + 3 * NH];
  }
  if (bias) {
    gi += bias[u]; gf += bias[u + NH]; gg += bias[u + 2 * NH]; go += bias[u + 3 * NH];
  }
  float si = 1.f / (1.f + expf(-gi));
  float sf = 1.f / (1.f + expf(-gf));
  float so = 1.f / (1.f + expf(-go));
  float tg = tanhf(gg);
  float cn = sf * cprev[b * NH + u] + si * tg;
  float hn = so * tanhf(cn);
  hout[b * NH + u] = hn;
  cout[b * NH + u] = cn;
}

// ---------------- fused attention: scores -> softmax -> context ------------
// one block per batch b. q=[32][1024], akey/enc_out rows (s*32+b).
__global__ __launch_bounds__(256) void attn_kernel(
    const float* __restrict__ q, const float* __restrict__ akey,
    const float* __restrict__ enc_out, float* __restrict__ ctx) {
  int b = blockIdx.x;
  __shared__ float qs[1024];
  __shared__ float sc[64];
  __shared__ float pr[64];
  int tid = threadIdx.x;
  *(float4*)&qs[tid * 4] = *(const float4*)&q[(size_t)b * NH + tid * 4];
  __syncthreads();
  int w = tid >> 6, lane = tid & 63;
  for (int ss = 0; ss < 16; ss++) {
    int s = w * 16 + ss;
    const float* krow = &akey[(size_t)(s * 32 + b) * NH];
    float p = 0.f;
#pragma unroll
    for (int i = 0; i < 4; i++) {
      int k4 = (lane + i * 64) * 4;
      float4 kq = *(const float4*)&qs[k4];
      float4 kk = *(const float4*)&krow[k4];
      p += kq.x * kk.x + kq.y * kk.y + kq.z * kk.z + kq.w * kk.w;
    }
    for (int off = 32; off; off >>= 1) p += __shfl_down(p, off);
    if (lane == 0) sc[s] = p;
  }
  __syncthreads();
  if (tid < 64) {
    float v = sc[tid];
    float m = v;
    for (int off = 32; off; off >>= 1) m = fmaxf(m, __shfl_xor(m, off));
    float e = expf(v - m);
    float sum = e;
    for (int off = 32; off; off >>= 1) sum += __shfl_xor(sum, off);
    pr[tid] = e / sum;
  }
  __syncthreads();
  float4 acc{0.f, 0.f, 0.f, 0.f};
  int h4 = tid * 4;
  for (int s = 0; s < 64; s++) {
    float p = pr[s];
    float4 e4 = *(const float4*)&enc_out[(size_t)(s * 32 + b) * NH + h4];
    acc.x += p * e4.x; acc.y += p * e4.y; acc.z += p * e4.z; acc.w += p * e4.w;
  }
  *(float4*)&ctx[(size_t)b * NH + h4] = acc;
}

}  // namespace

extern "C" void kernel_launch(void* const* d_in, const int* in_sizes, int n_in,
                              void* d_out, int out_size, void* d_ws, size_t ws_size,
                              hipStream_t stream) {
  (void)in_sizes; (void)n_in; (void)out_size; (void)ws_size;
  const int*   src   = (const int*)d_in[0];
  const int*   prev  = (const int*)d_in[1];
  const float* emb   = (const float*)d_in[2];
  const float* eWih0 = (const float*)d_in[3];
  const float* eWhh0 = (const float*)d_in[4];
  const float* eb0   = (const float*)d_in[5];
  const float* eWih1 = (const float*)d_in[6];
  const float* eWhh1 = (const float*)d_in[7];
  const float* eb1   = (const float*)d_in[8];
  const float* dWih0 = (const float*)d_in[9];
  const float* dWhh0 = (const float*)d_in[10];
  const float* db0   = (const float*)d_in[11];
  const float* dWih1 = (const float*)d_in[12];
  const float* dWhh1 = (const float*)d_in[13];
  const float* db1   = (const float*)d_in[14];
  const float* Wk    = (const float*)d_in[15];
  const float* bk    = (const float*)d_in[16];
  const float* Wh    = (const float*)d_in[17];
  const float* bh    = (const float*)d_in[18];
  float* out = (float*)d_out;

  float* ws = (float*)d_ws;
  constexpr size_t GX   = (size_t)2048 * 4096;
  constexpr size_t EM   = (size_t)2048 * 512;
  constexpr size_t HIST = (size_t)65 * 32 * 1024;
  constexpr size_t SLOT = (size_t)32 * 1024;
  float* gx  = ws;
  float* se  = gx + GX;
  float* te  = se + EM;
  float* y0h = te + EM;      // 8 contiguous history buffers start here
  float* c0h = y0h + HIST;
  float* y1h = c0h + HIST;
  float* c1h = y1h + HIST;
  float* dh0 = c1h + HIST;
  float* dc0 = dh0 + HIST;
  float* dh1 = dc0 + HIST;
  float* dc1 = dh1 + HIST;
  float* ak  = dc1 + HIST;
  float* ctx = ak + (size_t)2048 * 1024;

  zero_slot0<<<256, 256, 0, stream>>>(y0h);
  embed_kernel<<<2048, 256, 0, stream>>>(src, prev, emb, se, te);

  // encoder layer 0: input-gate GEMM then 64 recurrent steps
  gemm_tn<0><<<dim3(64, 32), 256, 0, stream>>>(se, 512, eWih0, 512, eb0, gx, 4096, 512);
  for (int s = 0; s < 64; s++) {
    lstm_step<0><<<128, 256, 0, stream>>>(gx + (size_t)s * 131072, nullptr,
        y0h + s * SLOT, eWhh0, 1024, nullptr, nullptr, 0,
        c0h + s * SLOT, y0h + (s + 1) * SLOT, c0h + (s + 1) * SLOT);
  }
  // encoder layer 1
  gemm_tn<0><<<dim3(64, 32), 256, 0, stream>>>(y0h + SLOT, 1024, eWih1, 1024, eb1, gx, 4096, 1024);
  for (int s = 0; s < 64; s++) {
    lstm_step<0><<<128, 256, 0, stream>>>(gx + (size_t)s * 131072, nullptr,
        y1h + s * SLOT, eWhh1, 1024, nullptr, nullptr, 0,
        c1h + s * SLOT, y1h + (s + 1) * SLOT, c1h + (s + 1) * SLOT);
  }
  // attention keys (constant over decoder steps)
  gemm_tn<0><<<dim3(16, 32), 256, 0, stream>>>(y1h + SLOT, 1024, Wk, 1024, bk, ak, 1024, 1024);
  // decoder layer0 input-part gates (xt through dec_Wih0[:, :512]) + bias
  gemm_tn<0><<<dim3(64, 32), 256, 0, stream>>>(te, 512, dWih0, 1536, db0, gx, 4096, 512);
  // decoder initial states = encoder finals
  init_dec_state<<<128, 256, 0, stream>>>(y0h + 64 * SLOT, c0h + 64 * SLOT,
                                          y1h + 64 * SLOT, c1h + 64 * SLOT,
                                          dh0, dc0, dh1, dc1);
  for (int t = 0; t < 64; t++) {
    attn_kernel<<<32, 256, 0, stream>>>(dh1 + t * SLOT, ak, y1h + SLOT, ctx);
    lstm_step<1><<<128, 256, 0, stream>>>(gx + (size_t)t * 131072, nullptr,
        ctx, dWih0 + 512, 1536, dh0 + t * SLOT, dWhh0, 1024,
        dc0 + t * SLOT, dh0 + (t + 1) * SLOT, dc0 + (t + 1) * SLOT);
    lstm_step<1><<<128, 256, 0, stream>>>(nullptr, db1,
        dh0 + (t + 1) * SLOT, dWih1, 1024, dh1 + t * SLOT, dWhh1, 1024,
        dc1 + t * SLOT, dh1 + (t + 1) * SLOT, dc1 + (t + 1) * SLOT);
  }
  // final logits: [2048,1024] x [1024,32000] scattered to out[b][t][v]
  gemm_tn<1><<<dim3(500, 32), 256, 0, stream>>>(dh1 + SLOT, 1024, Wh, 1024, bh, out, NV, 1024);
}

// Round 2
// 5170.649 us; speedup vs baseline: 3.1731x; 3.1731x over previous
//
#include <hip/hip_runtime.h>
#include <cmath>

namespace {

typedef short bs8 __attribute__((ext_vector_type(8)));
typedef float f32x4 __attribute__((ext_vector_type(4)));

constexpr int NV = 32000;
constexpr size_t SLOTH = 32 * 1024;   // elems per state slot (32 x 1024)

__device__ inline float b2f(unsigned short u) {
  union { unsigned int i; float f; } v; v.i = ((unsigned int)u) << 16; return v.f;
}
__device__ inline unsigned short f2b(float f) {
  unsigned int u = __float_as_uint(f);
  return (unsigned short)((u + 0x7FFFu + ((u >> 16) & 1u)) >> 16);
}

// ---------------- f32 -> bf16 weight conversion ----------------------------
__global__ __launch_bounds__(256) void cvt_kernel(
    const float* __restrict__ src, unsigned short* __restrict__ dst,
    int total8, int cols, int src_ld, int src_col0) {
  int idx = blockIdx.x * 256 + threadIdx.x;
  if (idx >= total8) return;
  int cpr = cols >> 3;
  int r = idx / cpr, c8 = (idx - r * cpr) * 8;
  const float* s = src + (size_t)r * src_ld + src_col0 + c8;
  float4 a = *(const float4*)s, b = *(const float4*)(s + 4);
  unsigned short o[8] = {f2b(a.x), f2b(a.y), f2b(a.z), f2b(a.w),
                         f2b(b.x), f2b(b.y), f2b(b.z), f2b(b.w)};
  *(bs8*)(dst + (size_t)r * cols + c8) = *(bs8*)o;
}

// ---------------- embedding gather -> bf16 ---------------------------------
__global__ __launch_bounds__(256) void embed_kernel(
    const int* __restrict__ src, const int* __restrict__ prev,
    const float* __restrict__ emb,
    unsigned short* __restrict__ se, unsigned short* __restrict__ te) {
  int idx = blockIdx.x * 256 + threadIdx.x;   // 0..262143
  int half = idx >> 17;
  int r = (idx >> 6) & 2047, c8 = (idx & 63) * 8;
  int s = r >> 5, b = r & 31;
  const int* tok = half ? prev : src;
  unsigned short* dst = half ? te : se;
  int t = tok[b * 64 + s];
  const float* e = emb + (size_t)t * 512 + c8;
  float4 a = *(const float4*)e, bb = *(const float4*)(e + 4);
  unsigned short o[8] = {f2b(a.x), f2b(a.y), f2b(a.z), f2b(a.w),
                         f2b(bb.x), f2b(bb.y), f2b(bb.z), f2b(bb.w)};
  *(bs8*)(dst + (size_t)r * 512 + c8) = *(bs8*)o;
}

// ---------------- zero slot0 / copy encoder finals -------------------------
__global__ __launch_bounds__(256) void zero_init(
    unsigned short* y0h, unsigned short* y1h, float* c0h, float* c1h) {
  int i = blockIdx.x * 256 + threadIdx.x;   // 32768 threads
  y0h[i] = 0; y1h[i] = 0; c0h[i] = 0.f; c1h[i] = 0.f;
}
__global__ __launch_bounds__(256) void init_dec(
    const unsigned short* __restrict__ y0f, const unsigned short* __restrict__ y1f,
    const float* __restrict__ c0f, const float* __restrict__ c1f,
    unsigned short* dh0, unsigned short* dh1, float* dc0, float* dc1) {
  int i = blockIdx.x * 256 + threadIdx.x;
  dh0[i] = y0f[i]; dh1[i] = y1f[i]; dc0[i] = c0f[i]; dc1[i] = c1f[i];
}

// ---------------- bf16 MFMA GEMM: C[M][N] = A[M][K] * B[N][K]^T + bias -----
// 128x128 tile, 256 threads (4 waves 2x2), BK=64, padded LDS (stride 72).
// OUTMODE 0: f32 C[m][ldc]; 1: f32 logits remap out[b][t][v]; 2: bf16 C.
template <int OUTMODE>
__global__ __launch_bounds__(256) void gemm_bf16(
    const unsigned short* __restrict__ A, int lda,
    const unsigned short* __restrict__ B, int ldb,
    const float* __restrict__ bias, void* __restrict__ Cp, int ldc, int K) {
  __shared__ unsigned short As[128 * 72];
  __shared__ unsigned short Bs[128 * 72];
  int tid = threadIdx.x;
  int m0 = blockIdx.x * 128, n0 = blockIdx.y * 128;
  int w = tid >> 6, l = tid & 63;
  int wr = w >> 1, wc = w & 1;
  f32x4 acc[4][4];
#pragma unroll
  for (int i = 0; i < 4; i++)
#pragma unroll
    for (int j = 0; j < 4; j++)
#pragma unroll
      for (int r = 0; r < 4; r++) acc[i][j][r] = 0.f;

  for (int k0 = 0; k0 < K; k0 += 64) {
    __syncthreads();
#pragma unroll
    for (int i = 0; i < 4; i++) {
      int idx = tid + i * 256;               // 0..1023
      int row = idx >> 3, c8 = (idx & 7) * 8;
      bs8 av = *(const bs8*)(A + (size_t)(m0 + row) * lda + k0 + c8);
      *(bs8*)&As[row * 72 + c8] = av;
      bs8 bv = *(const bs8*)(B + (size_t)(n0 + row) * ldb + k0 + c8);
      *(bs8*)&Bs[row * 72 + c8] = bv;
    }
    __syncthreads();
#pragma unroll
    for (int kk = 0; kk < 2; kk++) {
      bs8 af[4], bfr[4];
#pragma unroll
      for (int i = 0; i < 4; i++)
        af[i] = *(const bs8*)&As[(wr * 64 + i * 16 + (l & 15)) * 72 + kk * 32 + (l >> 4) * 8];
#pragma unroll
      for (int j = 0; j < 4; j++)
        bfr[j] = *(const bs8*)&Bs[(wc * 64 + j * 16 + (l & 15)) * 72 + kk * 32 + (l >> 4) * 8];
#pragma unroll
      for (int i = 0; i < 4; i++)
#pragma unroll
        for (int j = 0; j < 4; j++)
          acc[i][j] = __builtin_amdgcn_mfma_f32_16x16x32_bf16(af[i], bfr[j], acc[i][j], 0, 0, 0);
    }
  }
#pragma unroll
  for (int i = 0; i < 4; i++) {
    int mrow = m0 + wr * 64 + i * 16 + (l >> 4) * 4;
#pragma unroll
    for (int j = 0; j < 4; j++) {
      int n = n0 + wc * 64 + j * 16 + (l & 15);
      float bb = bias ? bias[n] : 0.f;
#pragma unroll
      for (int r = 0; r < 4; r++) {
        int m = mrow + r;
        float v = acc[i][j][r] + bb;
        if (OUTMODE == 1)
          ((float*)Cp)[(size_t)(m & 31) * (64ull * NV) + (size_t)(m >> 5) * NV + n] = v;
        else if (OUTMODE == 2)
          ((unsigned short*)Cp)[(size_t)m * ldc + n] = f2b(v);
        else
          ((float*)Cp)[(size_t)m * ldc + n] = v;
      }
    }
  }
}

// ---------------- MFMA LSTM step -------------------------------------------
// Grid 256 blocks x 64 threads (1 wave). Block covers u0=blockIdx*4:
// virtual cols 0..15 <-> (gate g = c>>2, unit u = u0 + (c&3)).
// G[32][16cols] = A1[32][1024] @ W1rows^T (+ A2 @ W2rows^T); fragments loaded
// directly from global (bf16, L2-hot weights). Then activations + state update.
template <int DUAL>
__global__ __launch_bounds__(64) void lstm_step_mfma(
    const unsigned short* __restrict__ A1, const unsigned short* __restrict__ W1,
    const unsigned short* __restrict__ A2, const unsigned short* __restrict__ W2,
    const float* __restrict__ gx, const float* __restrict__ bias,
    const float* __restrict__ cprev,
    unsigned short* __restrict__ hout, float* __restrict__ cout) {
  int l = threadIdx.x;
  int u0 = blockIdx.x * 4;
  int col = l & 15;
  int g = col >> 2, du = col & 3;
  int koff = (l >> 4) * 8;
  size_t wrow = ((size_t)g << 10) + u0 + du;
  const unsigned short* wp1 = W1 + wrow * 1024 + koff;
  const unsigned short* a1p = A1 + (size_t)col * 1024 + koff;
  f32x4 acc0, acc1;
#pragma unroll
  for (int r = 0; r < 4; r++) { acc0[r] = 0.f; acc1[r] = 0.f; }
#pragma unroll 4
  for (int kk = 0; kk < 1024; kk += 32) {
    bs8 b = *(const bs8*)(wp1 + kk);
    bs8 a0 = *(const bs8*)(a1p + kk);
    bs8 a1 = *(const bs8*)(a1p + 16 * 1024 + kk);
    acc0 = __builtin_amdgcn_mfma_f32_16x16x32_bf16(a0, b, acc0, 0, 0, 0);
    acc1 = __builtin_amdgcn_mfma_f32_16x16x32_bf16(a1, b, acc1, 0, 0, 0);
  }
  if (DUAL) {
    const unsigned short* wp2 = W2 + wrow * 1024 + koff;
    const unsigned short* a2p = A2 + (size_t)col * 1024 + koff;
#pragma unroll 4
    for (int kk = 0; kk < 1024; kk += 32) {
      bs8 b = *(const bs8*)(wp2 + kk);
      bs8 a0 = *(const bs8*)(a2p + kk);
      bs8 a1 = *(const bs8*)(a2p + 16 * 1024 + kk);
      acc0 = __builtin_amdgcn_mfma_f32_16x16x32_bf16(a0, b, acc0, 0, 0, 0);
      acc1 = __builtin_amdgcn_mfma_f32_16x16x32_bf16(a1, b, acc1, 0, 0, 0);
    }
  }
  __shared__ float lds[32][16];
#pragma unroll
  for (int r = 0; r < 4; r++) {
    lds[(l >> 4) * 4 + r][col] = acc0[r];
    lds[16 + (l >> 4) * 4 + r][col] = acc1[r];
  }
  __syncthreads();
#pragma unroll
  for (int p = 0; p < 2; p++) {
    int o = p * 64 + l;                       // 0..127 = 32 b x 4 u
    int b_ = o >> 2, ul = o & 3;
    int u = u0 + ul;
    float gi = lds[b_][0 * 4 + ul];
    float gf = lds[b_][1 * 4 + ul];
    float gg = lds[b_][2 * 4 + ul];
    float go = lds[b_][3 * 4 + ul];
    if (gx) {
      const float* gp = gx + (size_t)b_ * 4096 + u;
      gi += gp[0]; gf += gp[1024]; gg += gp[2048]; go += gp[3072];
    }
    if (bias) {
      gi += bias[u]; gf += bias[u + 1024]; gg += bias[u + 2048]; go += bias[u + 3072];
    }
    float si = 1.f / (1.f + expf(-gi));
    float sf = 1.f / (1.f + expf(-gf));
    float so = 1.f / (1.f + expf(-go));
    float tg = tanhf(gg);
    float cn = sf * cprev[b_ * 1024 + u] + si * tg;
    float hn = so * tanhf(cn);
    cout[b_ * 1024 + u] = cn;
    hout[b_ * 1024 + u] = f2b(hn);
  }
}

// ---------------- fused attention (bf16 in/out, fp32 math) -----------------
__global__ __launch_bounds__(256) void attn_kernel(
    const unsigned short* __restrict__ q, const unsigned short* __restrict__ akey,
    const unsigned short* __restrict__ enc, unsigned short* __restrict__ ctx) {
  int b = blockIdx.x;
  __shared__ float qs[1024];
  __shared__ float sc[64];
  __shared__ float pr[64];
  int tid = threadIdx.x;
  {
    ushort4 u4 = *(const ushort4*)&q[(size_t)b * 1024 + tid * 4];
    qs[tid * 4 + 0] = b2f(u4.x); qs[tid * 4 + 1] = b2f(u4.y);
    qs[tid * 4 + 2] = b2f(u4.z); qs[tid * 4 + 3] = b2f(u4.w);
  }
  __syncthreads();
  int w = tid >> 6, lane = tid & 63;
  for (int ss = 0; ss < 16; ss++) {
    int s = w * 16 + ss;
    const unsigned short* krow = &akey[(size_t)(s * 32 + b) * 1024];
    float p = 0.f;
#pragma unroll
    for (int i = 0; i < 4; i++) {
      int e = (lane + i * 64) * 4;
      ushort4 u4 = *(const ushort4*)&krow[e];
      p += qs[e] * b2f(u4.x) + qs[e + 1] * b2f(u4.y) +
           qs[e + 2] * b2f(u4.z) + qs[e + 3] * b2f(u4.w);
    }
    for (int off = 32; off; off >>= 1) p += __shfl_down(p, off);
    if (lane == 0) sc[s] = p;
  }
  __syncthreads();
  if (tid < 64) {
    float v = sc[tid];
    float m = v;
    for (int off = 32; off; off >>= 1) m = fmaxf(m, __shfl_xor(m, off));
    float e = expf(v - m);
    float sum = e;
    for (int off = 32; off; off >>= 1) sum += __shfl_xor(sum, off);
    pr[tid] = e / sum;
  }
  __syncthreads();
  float a0 = 0.f, a1 = 0.f, a2 = 0.f, a3 = 0.f;
  int h4 = tid * 4;
  for (int s = 0; s < 64; s++) {
    float p = pr[s];
    ushort4 u4 = *(const ushort4*)&enc[(size_t)(s * 32 + b) * 1024 + h4];
    a0 += p * b2f(u4.x); a1 += p * b2f(u4.y); a2 += p * b2f(u4.z); a3 += p * b2f(u4.w);
  }
  ushort4 o{f2b(a0), f2b(a1), f2b(a2), f2b(a3)};
  *(ushort4*)&ctx[(size_t)b * 1024 + h4] = o;
}

}  // namespace

extern "C" void kernel_launch(void* const* d_in, const int* in_sizes, int n_in,
                              void* d_out, int out_size, void* d_ws, size_t ws_size,
                              hipStream_t stream) {
  (void)in_sizes; (void)n_in; (void)out_size; (void)ws_size;
  const int*   src   = (const int*)d_in[0];
  const int*   prev  = (const int*)d_in[1];
  const float* emb   = (const float*)d_in[2];
  const float* eWih0 = (const float*)d_in[3];
  const float* eWhh0 = (const float*)d_in[4];
  const float* eb0   = (const float*)d_in[5];
  const float* eWih1 = (const float*)d_in[6];
  const float* eWhh1 = (const float*)d_in[7];
  const float* eb1   = (const float*)d_in[8];
  const float* dWih0 = (const float*)d_in[9];
  const float* dWhh0 = (const float*)d_in[10];
  const float* db0   = (const float*)d_in[11];
  const float* dWih1 = (const float*)d_in[12];
  const float* dWhh1 = (const float*)d_in[13];
  const float* db1   = (const float*)d_in[14];
  const float* Wk    = (const float*)d_in[15];
  const float* bk    = (const float*)d_in[16];
  const float* Wh    = (const float*)d_in[17];
  const float* bh    = (const float*)d_in[18];
  float* out = (float*)d_out;

  char* p = (char*)d_ws;
  auto alloc = [&](size_t bytes) {
    char* r = p; p += (bytes + 255) & ~(size_t)255; return r;
  };
  float* gx  = (float*)alloc(2048ull * 4096 * 4);
  float* c0h = (float*)alloc(65ull * SLOTH * 4);
  float* c1h = (float*)alloc(65ull * SLOTH * 4);
  float* dc0 = (float*)alloc(65ull * SLOTH * 4);
  float* dc1 = (float*)alloc(65ull * SLOTH * 4);
  unsigned short* y0h  = (unsigned short*)alloc(65ull * SLOTH * 2);
  unsigned short* y1h  = (unsigned short*)alloc(65ull * SLOTH * 2);
  unsigned short* dh0  = (unsigned short*)alloc(65ull * SLOTH * 2);
  unsigned short* dh1  = (unsigned short*)alloc(65ull * SLOTH * 2);
  unsigned short* se   = (unsigned short*)alloc(2048ull * 512 * 2);
  unsigned short* te   = (unsigned short*)alloc(2048ull * 512 * 2);
  unsigned short* ak   = (unsigned short*)alloc(2048ull * 1024 * 2);
  unsigned short* ctxb = (unsigned short*)alloc(32ull * 1024 * 2);
  unsigned short* wE0  = (unsigned short*)alloc(4096ull * 512 * 2);
  unsigned short* wH0  = (unsigned short*)alloc(4096ull * 1024 * 2);
  unsigned short* wE1  = (unsigned short*)alloc(4096ull * 1024 * 2);
  unsigned short* wH1  = (unsigned short*)alloc(4096ull * 1024 * 2);
  unsigned short* wD0x = (unsigned short*)alloc(4096ull * 512 * 2);
  unsigned short* wD0c = (unsigned short*)alloc(4096ull * 1024 * 2);
  unsigned short* wDh0 = (unsigned short*)alloc(4096ull * 1024 * 2);
  unsigned short* wD1  = (unsigned short*)alloc(4096ull * 1024 * 2);
  unsigned short* wDh1 = (unsigned short*)alloc(4096ull * 1024 * 2);
  unsigned short* wK   = (unsigned short*)alloc(1024ull * 1024 * 2);
  unsigned short* wV   = (unsigned short*)alloc((size_t)NV * 1024 * 2);

  // weight conversions (f32 -> bf16), independent
  cvt_kernel<<<1024, 256, 0, stream>>>(eWih0, wE0, 4096 * 64, 512, 512, 0);
  cvt_kernel<<<2048, 256, 0, stream>>>(eWhh0, wH0, 4096 * 128, 1024, 1024, 0);
  cvt_kernel<<<2048, 256, 0, stream>>>(eWih1, wE1, 4096 * 128, 1024, 1024, 0);
  cvt_kernel<<<2048, 256, 0, stream>>>(eWhh1, wH1, 4096 * 128, 1024, 1024, 0);
  cvt_kernel<<<1024, 256, 0, stream>>>(dWih0, wD0x, 4096 * 64, 512, 1536, 0);
  cvt_kernel<<<2048, 256, 0, stream>>>(dWih0, wD0c, 4096 * 128, 1024, 1536, 512);
  cvt_kernel<<<2048, 256, 0, stream>>>(dWhh0, wDh0, 4096 * 128, 1024, 1024, 0);
  cvt_kernel<<<2048, 256, 0, stream>>>(dWih1, wD1, 4096 * 128, 1024, 1024, 0);
  cvt_kernel<<<2048, 256, 0, stream>>>(dWhh1, wDh1, 4096 * 128, 1024, 1024, 0);
  cvt_kernel<<<512, 256, 0, stream>>>(Wk, wK, 1024 * 128, 1024, 1024, 0);
  cvt_kernel<<<16000, 256, 0, stream>>>(Wh, wV, NV * 128, 1024, 1024, 0);

  zero_init<<<128, 256, 0, stream>>>(y0h, y1h, c0h, c1h);
  embed_kernel<<<1024, 256, 0, stream>>>(src, prev, emb, se, te);

  // encoder layer 0
  gemm_bf16<0><<<dim3(16, 32), 256, 0, stream>>>(se, 512, wE0, 512, eb0, gx, 4096, 512);
  for (int s = 0; s < 64; s++)
    lstm_step_mfma<0><<<256, 64, 0, stream>>>(
        y0h + s * SLOTH, wH0, nullptr, nullptr, gx + (size_t)s * 131072, nullptr,
        c0h + s * SLOTH, y0h + (s + 1) * SLOTH, c0h + (s + 1) * SLOTH);
  // encoder layer 1
  gemm_bf16<0><<<dim3(16, 32), 256, 0, stream>>>(y0h + SLOTH, 1024, wE1, 1024, eb1, gx, 4096, 1024);
  for (int s = 0; s < 64; s++)
    lstm_step_mfma<0><<<256, 64, 0, stream>>>(
        y1h + s * SLOTH, wH1, nullptr, nullptr, gx + (size_t)s * 131072, nullptr,
        c1h + s * SLOTH, y1h + (s + 1) * SLOTH, c1h + (s + 1) * SLOTH);
  // attention keys (bf16 out)
  gemm_bf16<2><<<dim3(16, 8), 256, 0, stream>>>(y1h + SLOTH, 1024, wK, 1024, bk, ak, 1024, 1024);
  // decoder layer0 input-part gates (xt through dec_Wih0[:, :512]) + db0
  gemm_bf16<0><<<dim3(16, 32), 256, 0, stream>>>(te, 512, wD0x, 512, db0, gx, 4096, 512);
  // decoder initial states = encoder finals
  init_dec<<<128, 256, 0, stream>>>(y0h + 64 * SLOTH, y1h + 64 * SLOTH,
                                    c0h + 64 * SLOTH, c1h + 64 * SLOTH,
                                    dh0, dh1, dc0, dc1);
  for (int t = 0; t < 64; t++) {
    attn_kernel<<<32, 256, 0, stream>>>(dh1 + t * SLOTH, ak, y1h + SLOTH, ctxb);
    lstm_step_mfma<1><<<256, 64, 0, stream>>>(
        ctxb, wD0c, dh0 + t * SLOTH, wDh0, gx + (size_t)t * 131072, nullptr,
        dc0 + t * SLOTH, dh0 + (t + 1) * SLOTH, dc0 + (t + 1) * SLOTH);
    lstm_step_mfma<1><<<256, 64, 0, stream>>>(
        dh0 + (t + 1) * SLOTH, wD1, dh1 + t * SLOTH, wDh1, nullptr, db1,
        dc1 + t * SLOTH, dh1 + (t + 1) * SLOTH, dc1 + (t + 1) * SLOTH);
  }
  // final logits: [2048,1024] x [1024,32000]^T scattered to out[b][t][v]
  gemm_bf16<1><<<dim3(16, 250), 256, 0, stream>>>(dh1 + SLOTH, 1024, wV, 1024, bh, out, NV, 1024);
}